// Round 6
// baseline (425.310 us; speedup 1.0000x reference)
//
#include <hip/hip_runtime.h>
#include <hip/hip_bf16.h>

#define DEV __device__ __forceinline__

typedef __attribute__((ext_vector_type(8))) short bf16x8;
typedef __attribute__((ext_vector_type(4))) float f32x4;

// N=65536 tokens, 8 heads, head dim 32, feature dim 256, block 256
static constexpr float QSCALE = 0.17677669529663687f; // 1/sqrt(32)
static constexpr float LOG2E  = 1.4426950408889634f;

DEV unsigned short f2bf(float f) {
    union { float f; unsigned int u; } a; a.f = f;
    unsigned int r = (a.u + 0x7fffu + ((a.u >> 16) & 1u)) >> 16; // RNE
    return (unsigned short)r;
}
DEV unsigned int pack2bf(float lo, float hi) {   // v_cvt_pk_bf16_f32 on gfx950
    float2 t; t.x = lo; t.y = hi;
    __hip_bfloat162 h = __float22bfloat162_rn(t);
    unsigned int u; __builtin_memcpy(&u, &h, 4);
    return u;
}
DEV unsigned short f2bf1(float f) {              // 1 VALU (cvt_pk, keep low half)
    return (unsigned short)(pack2bf(f, 0.f) & 0xffffu);
}

// ---------------- pre-chain, 2 dispatches ----------------
// K1: block-local counting sort + keyarr + weight bf16 prep + w2 + done-counter reset.
__global__ __launch_bounds__(256) void kprep(
    const float* __restrict__ coords,
    const float* __restrict__ wq, const float* __restrict__ wk,
    const float* __restrict__ wv, const float* __restrict__ w_out,
    const float* __restrict__ ff1, const float* __restrict__ ff2,
    const float* __restrict__ w_rpe,
    unsigned int* __restrict__ hseg,        // [256 kblocks][256 buckets] packed
    unsigned int* __restrict__ locmemb,     // [256 kblocks][256] bucket-grouped ids
    unsigned int* __restrict__ keyarr,      // [65536] float bits of coords[:,0]
    unsigned int* __restrict__ done,        // [256] per-bucket arrival counters
    unsigned short* wqkvb, unsigned short* woutb,
    unsigned short* ff1b, unsigned short* ff2b, float* w2)
{
    __shared__ unsigned int lhist[256];
    __shared__ unsigned int s[256];
    __shared__ unsigned int loff[256];
    __shared__ float part[4];
    int tid = threadIdx.x;
    int g = blockIdx.x * 256 + tid;

    if (tid == 0) done[blockIdx.x] = 0u;
    lhist[tid] = 0u;
    float v = coords[(size_t)g * 3];
    keyarr[g] = __float_as_uint(v);          // keys >= 0 -> bit compare works
    int b8 = (int)(v * 256.0f);
    b8 = b8 < 0 ? 0 : (b8 > 255 ? 255 : b8);
    __syncthreads();
    unsigned int myl = atomicAdd(&lhist[b8], 1u);

    // independent work: weight conversion and w2
    if (g < 34816) {
        int i = g;
        if (i < 8192)        wqkvb[i] = f2bf(wq[i] * (QSCALE * LOG2E));
        else if (i < 16384)  wqkvb[i] = f2bf(wk[i - 8192]);
        else if (i < 24576)  wqkvb[i] = f2bf(wv[i - 16384]);
        else if (i < 32768)  woutb[i - 24576] = f2bf(w_out[i - 24576]);
        else if (i < 33792)  ff1b[i - 32768] = f2bf(ff1[i - 32768]);
        else                 ff2b[i - 33792] = f2bf(ff2[i - 33792]);
    }
    if (blockIdx.x >= 240) {                 // 16 blocks: w2[p], p = h*2 + c
        int p = blockIdx.x - 240;
        int h = p >> 1, c = p & 1;
        int d = tid >> 3, j = tid & 7;
        float w = w_rpe[(h * 32 + d) * 16 + c * 8 + j];
        float w2v = w * w;
        for (int m = 32; m >= 1; m >>= 1) w2v += __shfl_xor(w2v, m);
        if ((tid & 63) == 0) part[tid >> 6] = w2v;
        __syncthreads();
        if (tid == 0) w2[p] = (part[0] + part[1] + part[2] + part[3]) * (1.0f / 256.0f) * LOG2E;
    }
    __syncthreads();

    // block-local exclusive scan of bucket counts
    unsigned int cnt = lhist[tid];
    s[tid] = cnt; __syncthreads();
    for (int off = 1; off < 256; off <<= 1) {
        unsigned int t = (tid >= off) ? s[tid - off] : 0u;
        __syncthreads();
        s[tid] += t;
        __syncthreads();
    }
    unsigned int lexcl = s[tid] - cnt;
    loff[tid] = lexcl;
    hseg[blockIdx.x * 256 + tid] = (lexcl << 16) | cnt;   // coalesced, packed
    __syncthreads();

    // block-local bucket-grouped scatter
    locmemb[blockIdx.x * 256 + loff[b8] + myl] = (unsigned int)g;
}

// K2: one block per bucket, 512 threads
__global__ __launch_bounds__(512) void kbucket(
    const unsigned int* __restrict__ hseg,
    const unsigned int* __restrict__ locmemb,
    const unsigned int* __restrict__ keyarr,
    unsigned int* __restrict__ order)
{
    __shared__ unsigned int s[256];
    __shared__ unsigned int csum[512];
    __shared__ unsigned int mkey[512];
    __shared__ unsigned int midx[512];
    int tid = threadIdx.x;
    int b = blockIdx.x;
    int t8 = tid & 255, hi = tid >> 8;

    unsigned int tot = 0;
#pragma unroll 16
    for (int k = 0; k < 128; k++) tot += hseg[(hi * 128 + k) * 256 + t8] & 0xffffu;
    csum[tid] = tot;
    __syncthreads();
    if (tid < 256) s[tid] = csum[tid] + csum[tid + 256];
    __syncthreads();

    for (int off = 1; off < 256; off <<= 1) {
        unsigned int t = 0;
        if (tid < 256 && tid >= off) t = s[tid - off];
        __syncthreads();
        if (tid < 256) s[tid] += t;
        __syncthreads();
    }
    unsigned int start = (b == 0) ? 0u : s[b - 1];
    __syncthreads();

    unsigned int segcnt = 0, segoff = 0;
    if (tid < 256) {
        unsigned int pk = hseg[tid * 256 + b];
        segcnt = pk & 0xffffu;
        segoff = pk >> 16;
    }
    __syncthreads();
    if (tid < 256) s[tid] = segcnt;
    __syncthreads();
    for (int off = 1; off < 256; off <<= 1) {
        unsigned int t = 0;
        if (tid < 256 && tid >= off) t = s[tid - off];
        __syncthreads();
        if (tid < 256) s[tid] += t;
        __syncthreads();
    }
    unsigned int dst = (tid < 256) ? s[tid] - segcnt : 0u;
    unsigned int cntb = s[255];
    if (cntb > 512u) cntb = 512u;
    __syncthreads();

    if (tid < 256) {
        for (unsigned int j = 0; j < segcnt; j++) {
            unsigned int p = dst + j;
            if (p < 512u) midx[p] = locmemb[tid * 256 + segoff + j];
        }
    }
    __syncthreads();
    for (unsigned int p = tid; p < cntb; p += 512) mkey[p] = keyarr[midx[p]];
    __syncthreads();

    for (unsigned int m = tid; m < cntb; m += 512) {
        unsigned int km = mkey[m], im = midx[m];
        unsigned int r = 0;
        for (unsigned int j = 0; j < cntb; j++) {
            unsigned int kj = mkey[j];
            r += (kj < km || (kj == km && midx[j] < im)) ? 1u : 0u;
        }
        order[start + r] = im;
    }
}

// ---------------- per-(bucket,head) attention + last-arriver fused epilogue --------
// R6: back to R0's proven 2048-block regime (63.7 us core; 4-deep per-CU refill
// queue hides barrier drains that the 512-block fused version exposed), but the
// R0 aobf->kfinal round trip is replaced by a last-arriver epilogue: each block
// writes its head's scaled O (bf16, 16 KB) to aout, __threadfence + device-scope
// atomicAdd on done[bucket]; the 8th arriver runs out-proj + residual + LN2 +
// FFN + store for the whole bucket inline. No spin -> no deadlock; fixed
// reduction order -> deterministic. Block mapping keeps bh&7 invariant across a
// bucket's 8 heads -> all land on one XCD -> aout stays L2-local.
// LDS: xnb 16384 + Qb 16384 + Kb 16384 + Vt 16896 + kext 2048 + pf 2048
//      + Pst 9216 = 79360 B -> 2 blocks/CU.
__global__ __launch_bounds__(256, 2) void kbh(
    const float* __restrict__ x, const float* __restrict__ g1, const float* __restrict__ be1,
    const unsigned short* __restrict__ wqkvb,
    const unsigned int* __restrict__ order, const float* __restrict__ coords,
    const float* __restrict__ w2,
    const unsigned short* __restrict__ woutb, const float* __restrict__ b_out,
    const float* __restrict__ g2, const float* __restrict__ be2,
    const unsigned short* __restrict__ ff1b, const float* __restrict__ ffb1,
    const unsigned short* __restrict__ ff2b, const float* __restrict__ ffb2,
    unsigned short* __restrict__ aout, unsigned int* __restrict__ done,
    float* __restrict__ out)
{
    __shared__ unsigned short xnb[256][32];     // LN'd x, swizzled chunks
    __shared__ unsigned short Qb[256][32];      // swizzled chunks
    __shared__ unsigned short Kb[256][32];      // swizzled chunks
    __shared__ unsigned short Vt[32][264];      // [feature][permuted token]
    __shared__ unsigned short kext[256][4];     // {a, b, a^2, b^2} bf16
    __shared__ float2 pf[256];                  // f32 coords
    __shared__ unsigned short Pst[4][16][72];   // per-wave strip staging
    __shared__ unsigned int lastf;

    int bh = blockIdx.x;
    int p = bh & 255;
    int b = (p & 7) * 32 + (p >> 3);            // bucket; bh&7 fixed across heads
    int h = bh >> 8;                            // head
    int tid = threadIdx.x, wave = tid >> 6, lane = tid & 63;
    int col = lane & 15, quad = lane >> 4;

    // ---- stage A: gather x row, LN1 -> xnb (swizzled); coords -> kext/pf ----
    {
        int t = tid;
        int tok = (int)order[b * 256 + t];
        float a = coords[tok * 3 + 1], bb = coords[tok * 3 + 2];
        pf[t] = make_float2(a, bb);
        uint2 kv;
        kv.x = pack2bf(a, bb);
        kv.y = pack2bf(a * a, bb * bb);
        *(uint2*)&kext[t][0] = kv;

        float xv[32];
        const float4* xr = (const float4*)(x + (size_t)tok * 32);
#pragma unroll
        for (int q4 = 0; q4 < 8; q4++) {
            float4 v4 = xr[q4];
            xv[q4 * 4 + 0] = v4.x; xv[q4 * 4 + 1] = v4.y; xv[q4 * 4 + 2] = v4.z; xv[q4 * 4 + 3] = v4.w;
        }
        float mu = 0.f;
#pragma unroll
        for (int d = 0; d < 32; d++) mu += xv[d];
        mu *= (1.0f / 32.0f);
        float var = 0.f;
#pragma unroll
        for (int d = 0; d < 32; d++) { float c = xv[d] - mu; var += c * c; }
        var *= (1.0f / 32.0f);
        float rstd = rsqrtf(var + 1e-5f);
        unsigned int pk[16];
#pragma unroll
        for (int w = 0; w < 16; w++) {
            float a2 = (xv[2 * w] - mu) * rstd * g1[2 * w] + be1[2 * w];
            float b2 = (xv[2 * w + 1] - mu) * rstd * g1[2 * w + 1] + be1[2 * w + 1];
            pk[w] = pack2bf(a2, b2);
        }
        int v = (t >> 1) & 3;                    // chunk swizzle key
        uint4* dst = (uint4*)&xnb[t][0];
#pragma unroll
        for (int w4 = 0; w4 < 4; w4++) {
            uint4 v4; v4.x = pk[w4*4]; v4.y = pk[w4*4+1]; v4.z = pk[w4*4+2]; v4.w = pk[w4*4+3];
            dst[w4 ^ v] = v4;                    // logical chunk w4 -> physical w4^v
        }
    }

    // weight A-fragments for this head (global 16 B loads, L2-resident)
    bf16x8 wfr[6];
#pragma unroll
    for (int g = 0; g < 3; g++)
#pragma unroll
        for (int mt = 0; mt < 2; mt++)
            wfr[g * 2 + mt] = *(const bf16x8*)(wqkvb + (size_t)(g * 256 + h * 32 + mt * 16 + col) * 32 + quad * 8);

    __syncthreads();

    // ---- staging B: Q/K/V for all 256 tokens via MFMA ----
#pragma unroll
    for (int si = 0; si < 4; si++) {
        int token = wave * 64 + si * 16 + col;
        int vtk = (token >> 1) & 3;              // swizzle key
        bf16x8 bfx = *(const bf16x8*)&xnb[token][(quad ^ vtk) * 8];
        f32x4 zz = { 0.f, 0.f, 0.f, 0.f };
#pragma unroll
        for (int mt = 0; mt < 2; mt++) {
            f32x4 z = __builtin_amdgcn_mfma_f32_16x16x32_bf16(wfr[mt], bfx, zz, 0, 0, 0);
            uint2 u; u.x = pack2bf(z[0], z[1]); u.y = pack2bf(z[2], z[3]);
            int lc = 2 * mt + (quad >> 1);
            *(uint2*)&Qb[token][(lc ^ vtk) * 8 + (quad & 1) * 4] = u;
        }
#pragma unroll
        for (int mt = 0; mt < 2; mt++) {
            f32x4 z = __builtin_amdgcn_mfma_f32_16x16x32_bf16(wfr[2 + mt], bfx, zz, 0, 0, 0);
            uint2 u; u.x = pack2bf(z[0], z[1]); u.y = pack2bf(z[2], z[3]);
            int lc = 2 * mt + (quad >> 1);
            *(uint2*)&Kb[token][(lc ^ vtk) * 8 + (quad & 1) * 4] = u;
        }
        int jinv = (token & ~63) + (token & 15) * 4 + ((token >> 4) & 3);
#pragma unroll
        for (int mt = 0; mt < 2; mt++) {
            f32x4 z = __builtin_amdgcn_mfma_f32_16x16x32_bf16(wfr[4 + mt], bfx, zz, 0, 0, 0);
#pragma unroll
            for (int r = 0; r < 4; r++)
                Vt[mt * 16 + quad * 4 + r][jinv] = f2bf1(z[r]);
        }
    }
    __syncthreads();

    // extended-K fragments + V fragments hoisted to registers
    bf16x8 keext[16];
#pragma unroll
    for (int nt = 0; nt < 16; nt++) {
        uint2 kv = *(const uint2*)&kext[nt * 16 + col][0];
        unsigned int a0 = quad == 0 ? kv.x : 0u;
        unsigned int a1 = quad == 0 ? kv.y : 0u;
        bf16x8 f;
        f[0] = (short)(a0 & 0xffffu); f[1] = (short)(a0 >> 16);
        f[2] = (short)(a1 & 0xffffu); f[3] = (short)(a1 >> 16);
        f[4] = 0; f[5] = 0; f[6] = 0; f[7] = 0;
        keext[nt] = f;
    }
    bf16x8 vfr0[8], vfr1[8];
#pragma unroll
    for (int c = 0; c < 4; c++)
#pragma unroll
        for (int k2 = 0; k2 < 2; k2++) {
            vfr0[c * 2 + k2] = *(const bf16x8*)&Vt[col][c * 64 + k2 * 32 + quad * 8];
            vfr1[c * 2 + k2] = *(const bf16x8*)&Vt[16 + col][c * 64 + k2 * 32 + quad * 8];
        }

    float w0 = w2[2 * h], w1 = w2[2 * h + 1];   // already * log2e
    unsigned int qp1 = quad == 0 ? pack2bf(-w0, -w1) : 0u;
    int kswz = (quad ^ ((col >> 1) & 3)) * 8;   // Kb read swizzle

    // ---- 4 strips of 16 query rows per wave ----
#pragma unroll 1
    for (int si = 0; si < 4; si++) {
        int s = wave * 4 + si;
        int trow = s * 16 + col;
        bf16x8 qa = *(const bf16x8*)&Qb[trow][(quad ^ ((trow >> 1) & 3)) * 8];
        float2 pm = pf[trow];
        unsigned int qp0 = quad == 0 ? pack2bf(2.0f * w0 * pm.x, 2.0f * w1 * pm.y) : 0u;
        bf16x8 qe;
        qe[0] = (short)(qp0 & 0xffffu); qe[1] = (short)(qp0 >> 16);
        qe[2] = (short)(qp1 & 0xffffu); qe[3] = (short)(qp1 >> 16);
        qe[4] = 0; qe[5] = 0; qe[6] = 0; qe[7] = 0;

        f32x4 acc[16];
#pragma unroll
        for (int nt = 0; nt < 16; nt++) {
            bf16x8 kb = *(const bf16x8*)&Kb[nt * 16 + col][kswz];
            f32x4 z = { 0.f, 0.f, 0.f, 0.f };
            z = __builtin_amdgcn_mfma_f32_16x16x32_bf16(qa, kb, z, 0, 0, 0);
            acc[nt] = __builtin_amdgcn_mfma_f32_16x16x32_bf16(qe, keext[nt], z, 0, 0, 0);
        }

        float rsum[4] = { 0.f, 0.f, 0.f, 0.f };
        f32x4 o0 = { 0.f, 0.f, 0.f, 0.f }, o1 = { 0.f, 0.f, 0.f, 0.f };
#pragma unroll
        for (int c = 0; c < 4; c++) {
#pragma unroll
            for (int r = 0; r < 4; r++) {
                float e0 = __builtin_amdgcn_exp2f(acc[c * 4 + 0][r]);
                float e1 = __builtin_amdgcn_exp2f(acc[c * 4 + 1][r]);
                float e2 = __builtin_amdgcn_exp2f(acc[c * 4 + 2][r]);
                float e3 = __builtin_amdgcn_exp2f(acc[c * 4 + 3][r]);
                rsum[r] += (e0 + e1) + (e2 + e3);
                uint2 pk;
                pk.x = pack2bf(e0, e1);
                pk.y = pack2bf(e2, e3);
                *(uint2*)&Pst[wave][quad * 4 + r][col * 4] = pk;  // kloc = col*4+t
            }
#pragma unroll
            for (int k2 = 0; k2 < 2; k2++) {
                bf16x8 pa = *(const bf16x8*)&Pst[wave][col][k2 * 32 + quad * 8];
                o0 = __builtin_amdgcn_mfma_f32_16x16x32_bf16(pa, vfr0[c * 2 + k2], o0, 0, 0, 0);
                o1 = __builtin_amdgcn_mfma_f32_16x16x32_bf16(pa, vfr1[c * 2 + k2], o1, 0, 0, 0);
            }
        }

        // scale by 1/sum, stage O strip, full-line 16 B stores to aout
#pragma unroll
        for (int r = 0; r < 4; r++) {
            float su = rsum[r];
            su += __shfl_xor(su, 1); su += __shfl_xor(su, 2);
            su += __shfl_xor(su, 4); su += __shfl_xor(su, 8);
            float rl = __builtin_amdgcn_rcpf(su);
            Pst[wave][quad * 4 + r][col]      = f2bf1(o0[r] * rl);
            Pst[wave][quad * 4 + r][col + 16] = f2bf1(o1[r] * rl);
        }
        int orow = lane >> 2, opart = lane & 3;
        uint4 ov = *(const uint4*)&Pst[wave][orow][opart * 8];
        *(uint4*)(aout + (size_t)(b * 8 + h) * 8192 + (size_t)(s * 16 + orow) * 32 + opart * 8) = ov;
    }

    // ---- arrival protocol: 8th block of this bucket runs the epilogue ----
    __threadfence();                             // release own aout stores
    __syncthreads();
    if (tid == 0) lastf = (atomicAdd(&done[b], 1u) == 7u) ? 1u : 0u;
    __syncthreads();
    if (lastf == 0u) return;
    __threadfence();                             // acquire all 8 head slices

    // ---- epilogue: out-proj + b_out + residual, LN2, FFN, residual, store ----
    {
        bf16x8 wof[16];
#pragma unroll
        for (int ct = 0; ct < 2; ct++)
#pragma unroll
            for (int ks = 0; ks < 8; ks++)
                wof[ct * 8 + ks] = *(const bf16x8*)(woutb + (size_t)(ct * 16 + col) * 256 + ks * 32 + quad * 8);
        bf16x8 w1f[2], w2f[2];
#pragma unroll
        for (int ct = 0; ct < 2; ct++) {
            w1f[ct] = *(const bf16x8*)(ff1b + (ct * 16 + col) * 32 + quad * 8);
            w2f[ct] = *(const bf16x8*)(ff2b + (ct * 16 + col) * 32 + quad * 8);
        }
        float bo0 = b_out[col], bo1 = b_out[col + 16];
        float g20 = g2[col], g21 = g2[col + 16], be20 = be2[col], be21 = be2[col + 16];
        float fb10 = ffb1[col], fb11 = ffb1[col + 16];
        float fb20 = ffb2[col], fb21 = ffb2[col + 16];

#pragma unroll 1
        for (int rr = 0; rr < 4; rr++) {
            int rt = wave * 4 + rr;
            int rloc0 = rt * 16;

            f32x4 a0 = { 0.f, 0.f, 0.f, 0.f }, a1 = { 0.f, 0.f, 0.f, 0.f };
#pragma unroll
            for (int ks = 0; ks < 8; ks++) {
                bf16x8 af = *(const bf16x8*)(aout + (size_t)(b * 8 + ks) * 8192
                                             + (size_t)(rloc0 + col) * 32 + quad * 8);
                a0 = __builtin_amdgcn_mfma_f32_16x16x32_bf16(af, wof[ks], a0, 0, 0, 0);
                a1 = __builtin_amdgcn_mfma_f32_16x16x32_bf16(af, wof[8 + ks], a1, 0, 0, 0);
            }

            int trow[4];
#pragma unroll
            for (int r = 0; r < 4; r++) trow[r] = (int)order[b * 256 + rloc0 + quad * 4 + r];

#pragma unroll
            for (int r = 0; r < 4; r++) {
                a0[r] += x[(size_t)trow[r] * 32 + col] + bo0;
                a1[r] += x[(size_t)trow[r] * 32 + 16 + col] + bo1;
            }

            f32x4 xn0, xn1;
#pragma unroll
            for (int r = 0; r < 4; r++) {
                float s = a0[r] + a1[r];
                s += __shfl_xor(s, 1); s += __shfl_xor(s, 2); s += __shfl_xor(s, 4); s += __shfl_xor(s, 8);
                float mu = s * (1.0f / 32.0f);
                float c0 = a0[r] - mu, c1 = a1[r] - mu;
                float v = c0 * c0 + c1 * c1;
                v += __shfl_xor(v, 1); v += __shfl_xor(v, 2); v += __shfl_xor(v, 4); v += __shfl_xor(v, 8);
                float rstd = rsqrtf(v * (1.0f / 32.0f) + 1e-5f);
                xn0[r] = c0 * rstd * g20 + be20;
                xn1[r] = c1 * rstd * g21 + be21;
            }

#pragma unroll
            for (int r = 0; r < 4; r++) {
                Pst[wave][quad * 4 + r][col]      = f2bf1(xn0[r]);
                Pst[wave][quad * 4 + r][col + 16] = f2bf1(xn1[r]);
            }
            bf16x8 af1 = *(const bf16x8*)&Pst[wave][col][quad * 8];
            f32x4 z = { 0.f, 0.f, 0.f, 0.f };
            f32x4 h0 = __builtin_amdgcn_mfma_f32_16x16x32_bf16(af1, w1f[0], z, 0, 0, 0);
            f32x4 h1 = __builtin_amdgcn_mfma_f32_16x16x32_bf16(af1, w1f[1], z, 0, 0, 0);
#pragma unroll
            for (int r = 0; r < 4; r++) {
                h0[r] = fmaxf(h0[r] + fb10, 0.f);
                h1[r] = fmaxf(h1[r] + fb11, 0.f);
            }

#pragma unroll
            for (int r = 0; r < 4; r++) {
                Pst[wave][quad * 4 + r][col]      = f2bf1(h0[r]);
                Pst[wave][quad * 4 + r][col + 16] = f2bf1(h1[r]);
            }
            bf16x8 af2 = *(const bf16x8*)&Pst[wave][col][quad * 8];
            f32x4 f0 = __builtin_amdgcn_mfma_f32_16x16x32_bf16(af2, w2f[0], z, 0, 0, 0);
            f32x4 f1 = __builtin_amdgcn_mfma_f32_16x16x32_bf16(af2, w2f[1], z, 0, 0, 0);

#pragma unroll
            for (int r = 0; r < 4; r++) {
                out[(size_t)trow[r] * 32 + col]      = a0[r] + f0[r] + fb20;
                out[(size_t)trow[r] * 32 + 16 + col] = a1[r] + f1[r] + fb21;
            }
        }
    }
}

extern "C" void kernel_launch(void* const* d_in, const int* in_sizes, int n_in,
                              void* d_out, int out_size, void* d_ws, size_t ws_size,
                              hipStream_t stream) {
    (void)in_sizes; (void)n_in; (void)out_size; (void)ws_size;
    const float* x      = (const float*)d_in[0];
    const float* coords = (const float*)d_in[1];
    const float* wq     = (const float*)d_in[2];
    const float* wk     = (const float*)d_in[3];
    const float* wv     = (const float*)d_in[4];
    const float* w_rpe  = (const float*)d_in[5];
    const float* w_out  = (const float*)d_in[6];
    const float* b_out  = (const float*)d_in[7];
    const float* g1     = (const float*)d_in[8];
    const float* be1    = (const float*)d_in[9];
    const float* g2     = (const float*)d_in[10];
    const float* be2    = (const float*)d_in[11];
    const float* ffw1   = (const float*)d_in[12];
    const float* ffb1   = (const float*)d_in[13];
    const float* ffw2   = (const float*)d_in[14];
    const float* ffb2   = (const float*)d_in[15];
    float* out = (float*)d_out;

    char* ws = (char*)d_ws;
    unsigned int* hseg    = (unsigned int*)(ws);                     // 256 KB
    unsigned int* locmemb = (unsigned int*)(ws + 512 * 1024);        // 256 KB
    unsigned int* keyarr  = (unsigned int*)(ws + 768 * 1024);        // 256 KB
    unsigned int* order   = (unsigned int*)(ws + 1024 * 1024);       // 256 KB
    float*        w2      = (float*)(ws + 1280 * 1024);              // 16 f32
    unsigned int* done    = (unsigned int*)(ws + 1408 * 1024);       // 256 u32
    unsigned short* wqkvb = (unsigned short*)(ws + 1536 * 1024);     // 48 KB
    unsigned short* woutb = wqkvb + 24576;
    unsigned short* ff1b  = woutb + 8192;
    unsigned short* ff2b  = ff1b + 1024;
    unsigned short* aout  = (unsigned short*)(ws + (size_t)100 * 1048576); // 32 MiB

    kprep  <<<256, 256, 0, stream>>>(coords, wq, wk, wv, w_out, ffw1, ffw2, w_rpe,
                                     hseg, locmemb, keyarr, done,
                                     wqkvb, woutb, ff1b, ff2b, w2);
    kbucket<<<256, 512, 0, stream>>>(hseg, locmemb, keyarr, order);
    kbh    <<<2048, 256, 0, stream>>>(x, g1, be1, wqkvb, order, coords, w2,
                                      woutb, b_out, g2, be2,
                                      ff1b, ffb1, ff2b, ffb2, aout, done, out);
}

// Round 7
// 178.337 us; speedup vs baseline: 2.3849x; 2.3849x over previous
//
#include <hip/hip_runtime.h>
#include <hip/hip_bf16.h>

#define DEV __device__ __forceinline__

typedef __attribute__((ext_vector_type(8))) short bf16x8;
typedef __attribute__((ext_vector_type(4))) float f32x4;

// N=65536 tokens, 8 heads, head dim 32, feature dim 256, block 256
static constexpr float QSCALE = 0.17677669529663687f; // 1/sqrt(32)
static constexpr float LOG2E  = 1.4426950408889634f;

DEV unsigned short f2bf(float f) {
    union { float f; unsigned int u; } a; a.f = f;
    unsigned int r = (a.u + 0x7fffu + ((a.u >> 16) & 1u)) >> 16; // RNE
    return (unsigned short)r;
}
DEV unsigned int pack2bf(float lo, float hi) {   // v_cvt_pk_bf16_f32 on gfx950
    float2 t; t.x = lo; t.y = hi;
    __hip_bfloat162 h = __float22bfloat162_rn(t);
    unsigned int u; __builtin_memcpy(&u, &h, 4);
    return u;
}
DEV unsigned short f2bf1(float f) {              // 1 VALU (cvt_pk, keep low half)
    return (unsigned short)(pack2bf(f, 0.f) & 0xffffu);
}

// ---------------- pre-chain, 2 dispatches (R5-proven) ----------------
__global__ __launch_bounds__(256) void kprep(
    const float* __restrict__ coords,
    const float* __restrict__ wq, const float* __restrict__ wk,
    const float* __restrict__ wv, const float* __restrict__ w_out,
    const float* __restrict__ ff1, const float* __restrict__ ff2,
    const float* __restrict__ w_rpe,
    unsigned int* __restrict__ hseg,        // [256 kblocks][256 buckets] packed
    unsigned int* __restrict__ locmemb,     // [256 kblocks][256] bucket-grouped ids
    unsigned int* __restrict__ keyarr,      // [65536] float bits of coords[:,0]
    unsigned short* wqkvb, unsigned short* woutb,
    unsigned short* ff1b, unsigned short* ff2b, float* w2)
{
    __shared__ unsigned int lhist[256];
    __shared__ unsigned int s[256];
    __shared__ unsigned int loff[256];
    __shared__ float part[4];
    int tid = threadIdx.x;
    int g = blockIdx.x * 256 + tid;

    lhist[tid] = 0u;
    float v = coords[(size_t)g * 3];
    keyarr[g] = __float_as_uint(v);          // keys >= 0 -> bit compare works
    int b8 = (int)(v * 256.0f);
    b8 = b8 < 0 ? 0 : (b8 > 255 ? 255 : b8);
    __syncthreads();
    unsigned int myl = atomicAdd(&lhist[b8], 1u);

    if (g < 34816) {
        int i = g;
        if (i < 8192)        wqkvb[i] = f2bf(wq[i] * (QSCALE * LOG2E));
        else if (i < 16384)  wqkvb[i] = f2bf(wk[i - 8192]);
        else if (i < 24576)  wqkvb[i] = f2bf(wv[i - 16384]);
        else if (i < 32768)  woutb[i - 24576] = f2bf(w_out[i - 24576]);
        else if (i < 33792)  ff1b[i - 32768] = f2bf(ff1[i - 32768]);
        else                 ff2b[i - 33792] = f2bf(ff2[i - 33792]);
    }
    if (blockIdx.x >= 240) {                 // 16 blocks: w2[p], p = h*2 + c
        int p = blockIdx.x - 240;
        int h = p >> 1, c = p & 1;
        int d = tid >> 3, j = tid & 7;
        float w = w_rpe[(h * 32 + d) * 16 + c * 8 + j];
        float w2v = w * w;
        for (int m = 32; m >= 1; m >>= 1) w2v += __shfl_xor(w2v, m);
        if ((tid & 63) == 0) part[tid >> 6] = w2v;
        __syncthreads();
        if (tid == 0) w2[p] = (part[0] + part[1] + part[2] + part[3]) * (1.0f / 256.0f) * LOG2E;
    }
    __syncthreads();

    unsigned int cnt = lhist[tid];
    s[tid] = cnt; __syncthreads();
    for (int off = 1; off < 256; off <<= 1) {
        unsigned int t = (tid >= off) ? s[tid - off] : 0u;
        __syncthreads();
        s[tid] += t;
        __syncthreads();
    }
    unsigned int lexcl = s[tid] - cnt;
    loff[tid] = lexcl;
    hseg[blockIdx.x * 256 + tid] = (lexcl << 16) | cnt;   // coalesced, packed
    __syncthreads();

    locmemb[blockIdx.x * 256 + loff[b8] + myl] = (unsigned int)g;
}

__global__ __launch_bounds__(512) void kbucket(
    const unsigned int* __restrict__ hseg,
    const unsigned int* __restrict__ locmemb,
    const unsigned int* __restrict__ keyarr,
    unsigned int* __restrict__ order)
{
    __shared__ unsigned int s[256];
    __shared__ unsigned int csum[512];
    __shared__ unsigned int mkey[512];
    __shared__ unsigned int midx[512];
    int tid = threadIdx.x;
    int b = blockIdx.x;
    int t8 = tid & 255, hi = tid >> 8;

    unsigned int tot = 0;
#pragma unroll 16
    for (int k = 0; k < 128; k++) tot += hseg[(hi * 128 + k) * 256 + t8] & 0xffffu;
    csum[tid] = tot;
    __syncthreads();
    if (tid < 256) s[tid] = csum[tid] + csum[tid + 256];
    __syncthreads();

    for (int off = 1; off < 256; off <<= 1) {
        unsigned int t = 0;
        if (tid < 256 && tid >= off) t = s[tid - off];
        __syncthreads();
        if (tid < 256) s[tid] += t;
        __syncthreads();
    }
    unsigned int start = (b == 0) ? 0u : s[b - 1];
    __syncthreads();

    unsigned int segcnt = 0, segoff = 0;
    if (tid < 256) {
        unsigned int pk = hseg[tid * 256 + b];
        segcnt = pk & 0xffffu;
        segoff = pk >> 16;
    }
    __syncthreads();
    if (tid < 256) s[tid] = segcnt;
    __syncthreads();
    for (int off = 1; off < 256; off <<= 1) {
        unsigned int t = 0;
        if (tid < 256 && tid >= off) t = s[tid - off];
        __syncthreads();
        if (tid < 256) s[tid] += t;
        __syncthreads();
    }
    unsigned int dst = (tid < 256) ? s[tid] - segcnt : 0u;
    unsigned int cntb = s[255];
    if (cntb > 512u) cntb = 512u;
    __syncthreads();

    if (tid < 256) {
        for (unsigned int j = 0; j < segcnt; j++) {
            unsigned int p = dst + j;
            if (p < 512u) midx[p] = locmemb[tid * 256 + segoff + j];
        }
    }
    __syncthreads();
    for (unsigned int p = tid; p < cntb; p += 512) mkey[p] = keyarr[midx[p]];
    __syncthreads();

    for (unsigned int m = tid; m < cntb; m += 512) {
        unsigned int km = mkey[m], im = midx[m];
        unsigned int r = 0;
        for (unsigned int j = 0; j < cntb; j++) {
            unsigned int kj = mkey[j];
            r += (kj < km || (kj == km && midx[j] < im)) ? 1u : 0u;
        }
        order[start + r] = im;
    }
}

// ---------------- fully fused attention, quarter-split for occupancy ----------------
// R7: grid 1024 = 256 buckets x 4 query-quarters (64 q-rows each), 256 threads.
// R6's fence-based last-arriver was catastrophic (device-scope release/acquire =
// cross-XCD L2 writeback; 332 us) -- reverted. R5's 19% occupancy was GRID-capped
// (512 blocks = 2/CU, no refill). This version cuts LDS 80.4 -> 49.5 KB so
// 3 blocks/CU fit, with grid 1024 providing a refill queue (target 12 waves/CU).
// Key moves:
//  - xnb eliminated: stage A writes LN'd x into a TRANSIENT overlay of Kb; a
//    one-time pre-loop phase pulls each wave's 4 head-invariant B-fragments into
//    registers (compile-time indexed); head-0's K staging then overwrites Kb.
//  - 1 strip/wave -> keext/vfr register hoists (which amortized across strips)
//    moved inline, freeing ~128 VGPRs -> fits 3 waves/SIMD (launch_bounds(256,3)).
//  - K/V staged per quarter (x4 total, +~13% MFMA) -- paid by 1.5x occupancy.
// LDS: KbX 16384 + Qb 4096 + Vt 16896 + kext 2048 + pf 2048 + Pst 9216
//      = 50688 <= 54272 (160K/3, 512B granularity) -> 3 blocks/CU.
__global__ __launch_bounds__(256, 3) void kattn(
    const float* __restrict__ x, const float* __restrict__ g1, const float* __restrict__ be1,
    const unsigned short* __restrict__ wqkvb,
    const unsigned int* __restrict__ order, const float* __restrict__ coords,
    const float* __restrict__ w2,
    const unsigned short* __restrict__ woutb, const float* __restrict__ b_out,
    const float* __restrict__ g2, const float* __restrict__ be2,
    const unsigned short* __restrict__ ff1b, const float* __restrict__ ffb1,
    const unsigned short* __restrict__ ff2b, const float* __restrict__ ffb2,
    float* __restrict__ out)
{
    __shared__ unsigned short KbX[256][32];      // 16384 B  xnb (transient) then Kb
    __shared__ unsigned short Qb[64][32];        //  4096 B  this quarter's Q, swizzled
    __shared__ unsigned short Vt[32][264];       // 16896 B  [feature][permuted token]
    __shared__ unsigned short kext[256][4];      //  2048 B  {a, b, a^2, b^2} bf16
    __shared__ float2 pf[256];                   //  2048 B  f32 coords for Q side
    __shared__ unsigned short Pst[4][16][72];    //  9216 B  per-wave strip staging

    int bh = blockIdx.x;
    int p = bh & 255;
    int b = (p & 7) * 32 + (p >> 3);            // bucket; all 4 quarters share bh&7 (XCD)
    int qbase = (bh >> 8) * 64;                 // query-row window base (0/64/128/192)
    int tid = threadIdx.x, wave = tid >> 6, lane = tid & 63;
    int col = lane & 15, quad = lane >> 4;

    // ---- stage A: gather x row, LN1 -> KbX overlay (swizzled); coords -> kext/pf ----
    {
        int t = tid;
        int tok = (int)order[b * 256 + t];
        float a = coords[tok * 3 + 1], bb = coords[tok * 3 + 2];
        pf[t] = make_float2(a, bb);
        uint2 kv;
        kv.x = pack2bf(a, bb);
        kv.y = pack2bf(a * a, bb * bb);
        *(uint2*)&kext[t][0] = kv;

        float xv[32];
        const float4* xr = (const float4*)(x + (size_t)tok * 32);
#pragma unroll
        for (int q4 = 0; q4 < 8; q4++) {
            float4 v4 = xr[q4];
            xv[q4 * 4 + 0] = v4.x; xv[q4 * 4 + 1] = v4.y; xv[q4 * 4 + 2] = v4.z; xv[q4 * 4 + 3] = v4.w;
        }
        float mu = 0.f;
#pragma unroll
        for (int d = 0; d < 32; d++) mu += xv[d];
        mu *= (1.0f / 32.0f);
        float var = 0.f;
#pragma unroll
        for (int d = 0; d < 32; d++) { float c = xv[d] - mu; var += c * c; }
        var *= (1.0f / 32.0f);
        float rstd = rsqrtf(var + 1e-5f);
        unsigned int pk[16];
#pragma unroll
        for (int w = 0; w < 16; w++) {
            float a2 = (xv[2 * w] - mu) * rstd * g1[2 * w] + be1[2 * w];
            float b2 = (xv[2 * w + 1] - mu) * rstd * g1[2 * w + 1] + be1[2 * w + 1];
            pk[w] = pack2bf(a2, b2);
        }
        int v = (t >> 1) & 3;                    // chunk swizzle key
        uint4* dst = (uint4*)&KbX[t][0];
#pragma unroll
        for (int w4 = 0; w4 < 4; w4++) {
            uint4 v4; v4.x = pk[w4*4]; v4.y = pk[w4*4+1]; v4.z = pk[w4*4+2]; v4.w = pk[w4*4+3];
            dst[w4 ^ v] = v4;                    // logical chunk w4 -> physical w4^v
        }
    }
    __syncthreads();

    // ---- stage A2: pull this wave's 4 head-invariant B-fragments to registers ----
    bf16x8 bfx4[4];
#pragma unroll
    for (int si = 0; si < 4; si++) {
        int token = wave * 64 + si * 16 + col;
        int vtk = (token >> 1) & 3;
        bfx4[si] = *(const bf16x8*)&KbX[token][(quad ^ vtk) * 8];
    }
    __syncthreads();                             // KbX free to be overwritten as Kb

    // out-proj accumulators: 1 strip x 32 out-features, f32, live across heads
    f32x4 aggr0 = { 0.f, 0.f, 0.f, 0.f }, aggr1 = { 0.f, 0.f, 0.f, 0.f };

    int kswz = (quad ^ ((col >> 1) & 3)) * 8;    // Kb read swizzle (row = nt*16+col)

#pragma unroll 1
    for (int h = 0; h < 8; h++) {
        // weight A-fragments for this head (global 16 B loads, L2-resident)
        bf16x8 wfr[6];
#pragma unroll
        for (int g = 0; g < 3; g++)
#pragma unroll
            for (int mt = 0; mt < 2; mt++)
                wfr[g * 2 + mt] = *(const bf16x8*)(wqkvb + (size_t)(g * 256 + h * 32 + mt * 16 + col) * 32 + quad * 8);

        if (h) __syncthreads();                  // prev head's strip readers done

        // ---- staging B: K/V for all 256 tokens, Q for this quarter's 64 rows ----
#pragma unroll
        for (int si = 0; si < 4; si++) {
            int token = wave * 64 + si * 16 + col;
            int vtk = (token >> 1) & 3;
            bf16x8 bfx = bfx4[si];
            f32x4 zz = { 0.f, 0.f, 0.f, 0.f };
            if (token >= qbase && token < qbase + 64) {
                int tq = token - qbase;
#pragma unroll
                for (int mt = 0; mt < 2; mt++) {
                    f32x4 z = __builtin_amdgcn_mfma_f32_16x16x32_bf16(wfr[mt], bfx, zz, 0, 0, 0);
                    uint2 u; u.x = pack2bf(z[0], z[1]); u.y = pack2bf(z[2], z[3]);
                    int lc = 2 * mt + (quad >> 1);
                    *(uint2*)&Qb[tq][(lc ^ vtk) * 8 + (quad & 1) * 4] = u;
                }
            }
#pragma unroll
            for (int mt = 0; mt < 2; mt++) {
                f32x4 z = __builtin_amdgcn_mfma_f32_16x16x32_bf16(wfr[2 + mt], bfx, zz, 0, 0, 0);
                uint2 u; u.x = pack2bf(z[0], z[1]); u.y = pack2bf(z[2], z[3]);
                int lc = 2 * mt + (quad >> 1);
                *(uint2*)&KbX[token][(lc ^ vtk) * 8 + (quad & 1) * 4] = u;
            }
            int jinv = (token & ~63) + (token & 15) * 4 + ((token >> 4) & 3);
#pragma unroll
            for (int mt = 0; mt < 2; mt++) {
                f32x4 z = __builtin_amdgcn_mfma_f32_16x16x32_bf16(wfr[4 + mt], bfx, zz, 0, 0, 0);
#pragma unroll
                for (int r = 0; r < 4; r++)
                    Vt[mt * 16 + quad * 4 + r][jinv] = f2bf1(z[r]);
            }
        }
        __syncthreads();

        float w0 = w2[2 * h], w1 = w2[2 * h + 1];   // already * log2e
        bf16x8 wof0 = *(const bf16x8*)(woutb + (size_t)col * 256 + h * 32 + quad * 8);
        bf16x8 wof1 = *(const bf16x8*)(woutb + (size_t)(16 + col) * 256 + h * 32 + quad * 8);
        unsigned int qp1 = quad == 0 ? pack2bf(-w0, -w1) : 0u;

        // ---- 1 strip of 16 query rows per wave ----
        int trow = qbase + wave * 16 + col;          // global row in bucket
        bf16x8 qa = *(const bf16x8*)&Qb[wave * 16 + col][(quad ^ ((trow >> 1) & 3)) * 8];
        float2 pm = pf[trow];
        unsigned int qp0 = quad == 0 ? pack2bf(2.0f * w0 * pm.x, 2.0f * w1 * pm.y) : 0u;
        bf16x8 qe;
        qe[0] = (short)(qp0 & 0xffffu); qe[1] = (short)(qp0 >> 16);
        qe[2] = (short)(qp1 & 0xffffu); qe[3] = (short)(qp1 >> 16);
        qe[4] = 0; qe[5] = 0; qe[6] = 0; qe[7] = 0;

        f32x4 acc[16];
#pragma unroll
        for (int nt = 0; nt < 16; nt++) {
            bf16x8 kb = *(const bf16x8*)&KbX[nt * 16 + col][kswz];
            uint2 kv = *(const uint2*)&kext[nt * 16 + col][0];
            unsigned int ea0 = quad == 0 ? kv.x : 0u;
            unsigned int ea1 = quad == 0 ? kv.y : 0u;
            bf16x8 ke;
            ke[0] = (short)(ea0 & 0xffffu); ke[1] = (short)(ea0 >> 16);
            ke[2] = (short)(ea1 & 0xffffu); ke[3] = (short)(ea1 >> 16);
            ke[4] = 0; ke[5] = 0; ke[6] = 0; ke[7] = 0;
            f32x4 z = { 0.f, 0.f, 0.f, 0.f };
            z = __builtin_amdgcn_mfma_f32_16x16x32_bf16(qa, kb, z, 0, 0, 0);
            acc[nt] = __builtin_amdgcn_mfma_f32_16x16x32_bf16(qe, ke, z, 0, 0, 0);
        }

        // scores in log2 domain -> hardware exp2
        float rsum[4] = { 0.f, 0.f, 0.f, 0.f };
        f32x4 o0 = { 0.f, 0.f, 0.f, 0.f }, o1 = { 0.f, 0.f, 0.f, 0.f };
#pragma unroll
        for (int c = 0; c < 4; c++) {
#pragma unroll
            for (int r = 0; r < 4; r++) {
                float e0 = __builtin_amdgcn_exp2f(acc[c * 4 + 0][r]);
                float e1 = __builtin_amdgcn_exp2f(acc[c * 4 + 1][r]);
                float e2 = __builtin_amdgcn_exp2f(acc[c * 4 + 2][r]);
                float e3 = __builtin_amdgcn_exp2f(acc[c * 4 + 3][r]);
                rsum[r] += (e0 + e1) + (e2 + e3);
                uint2 pk;
                pk.x = pack2bf(e0, e1);
                pk.y = pack2bf(e2, e3);
                *(uint2*)&Pst[wave][quad * 4 + r][col * 4] = pk;  // kloc = col*4+t
            }
#pragma unroll
            for (int k2 = 0; k2 < 2; k2++) {
                bf16x8 pa  = *(const bf16x8*)&Pst[wave][col][k2 * 32 + quad * 8];
                bf16x8 v0f = *(const bf16x8*)&Vt[col][c * 64 + k2 * 32 + quad * 8];
                bf16x8 v1f = *(const bf16x8*)&Vt[16 + col][c * 64 + k2 * 32 + quad * 8];
                o0 = __builtin_amdgcn_mfma_f32_16x16x32_bf16(pa, v0f, o0, 0, 0, 0);
                o1 = __builtin_amdgcn_mfma_f32_16x16x32_bf16(pa, v1f, o1, 0, 0, 0);
            }
        }

        // scale by 1/sum, stage O strip, out-proj accumulate
#pragma unroll
        for (int r = 0; r < 4; r++) {
            float su = rsum[r];
            su += __shfl_xor(su, 1); su += __shfl_xor(su, 2);
            su += __shfl_xor(su, 4); su += __shfl_xor(su, 8);
            float rl = __builtin_amdgcn_rcpf(su);
            Pst[wave][quad * 4 + r][col]      = f2bf1(o0[r] * rl);
            Pst[wave][quad * 4 + r][col + 16] = f2bf1(o1[r] * rl);
        }
        bf16x8 af = *(const bf16x8*)&Pst[wave][col][quad * 8];
        aggr0 = __builtin_amdgcn_mfma_f32_16x16x32_bf16(af, wof0, aggr0, 0, 0, 0);
        aggr1 = __builtin_amdgcn_mfma_f32_16x16x32_bf16(af, wof1, aggr1, 0, 0, 0);
    }

    // ---- epilogue: + b_out + residual, LN2, FFN, residual, scatter store ----
    {
        bf16x8 w1f[2], w2f[2];
#pragma unroll
        for (int ct = 0; ct < 2; ct++) {
            w1f[ct] = *(const bf16x8*)(ff1b + (ct * 16 + col) * 32 + quad * 8);
            w2f[ct] = *(const bf16x8*)(ff2b + (ct * 16 + col) * 32 + quad * 8);
        }
        float bo0 = b_out[col], bo1 = b_out[col + 16];
        float g20 = g2[col], g21 = g2[col + 16], be20 = be2[col], be21 = be2[col + 16];
        float fb10 = ffb1[col], fb11 = ffb1[col + 16];
        float fb20 = ffb2[col], fb21 = ffb2[col + 16];

        int rloc0 = qbase + wave * 16;            // sorted-local row base (own strip)
        f32x4 a0 = aggr0, a1 = aggr1;
        int trow[4];
#pragma unroll
        for (int r = 0; r < 4; r++) trow[r] = (int)order[b * 256 + rloc0 + quad * 4 + r];

#pragma unroll
        for (int r = 0; r < 4; r++) {
            a0[r] += x[(size_t)trow[r] * 32 + col] + bo0;
            a1[r] += x[(size_t)trow[r] * 32 + 16 + col] + bo1;
        }

        f32x4 xn0, xn1;
#pragma unroll
        for (int r = 0; r < 4; r++) {
            float s = a0[r] + a1[r];
            s += __shfl_xor(s, 1); s += __shfl_xor(s, 2); s += __shfl_xor(s, 4); s += __shfl_xor(s, 8);
            float mu = s * (1.0f / 32.0f);
            float c0 = a0[r] - mu, c1 = a1[r] - mu;
            float v = c0 * c0 + c1 * c1;
            v += __shfl_xor(v, 1); v += __shfl_xor(v, 2); v += __shfl_xor(v, 4); v += __shfl_xor(v, 8);
            float rstd = rsqrtf(v * (1.0f / 32.0f) + 1e-5f);
            xn0[r] = c0 * rstd * g20 + be20;
            xn1[r] = c1 * rstd * g21 + be21;
        }

#pragma unroll
        for (int r = 0; r < 4; r++) {
            Pst[wave][quad * 4 + r][col]      = f2bf1(xn0[r]);
            Pst[wave][quad * 4 + r][col + 16] = f2bf1(xn1[r]);
        }
        bf16x8 af1 = *(const bf16x8*)&Pst[wave][col][quad * 8];
        f32x4 z = { 0.f, 0.f, 0.f, 0.f };
        f32x4 h0 = __builtin_amdgcn_mfma_f32_16x16x32_bf16(af1, w1f[0], z, 0, 0, 0);
        f32x4 h1 = __builtin_amdgcn_mfma_f32_16x16x32_bf16(af1, w1f[1], z, 0, 0, 0);
#pragma unroll
        for (int r = 0; r < 4; r++) {
            h0[r] = fmaxf(h0[r] + fb10, 0.f);
            h1[r] = fmaxf(h1[r] + fb11, 0.f);
        }

#pragma unroll
        for (int r = 0; r < 4; r++) {
            Pst[wave][quad * 4 + r][col]      = f2bf1(h0[r]);
            Pst[wave][quad * 4 + r][col + 16] = f2bf1(h1[r]);
        }
        bf16x8 af2 = *(const bf16x8*)&Pst[wave][col][quad * 8];
        f32x4 f0 = __builtin_amdgcn_mfma_f32_16x16x32_bf16(af2, w2f[0], z, 0, 0, 0);
        f32x4 f1 = __builtin_amdgcn_mfma_f32_16x16x32_bf16(af2, w2f[1], z, 0, 0, 0);

#pragma unroll
        for (int r = 0; r < 4; r++) {
            out[(size_t)trow[r] * 32 + col]      = a0[r] + f0[r] + fb20;
            out[(size_t)trow[r] * 32 + 16 + col] = a1[r] + f1[r] + fb21;
        }
    }
}

extern "C" void kernel_launch(void* const* d_in, const int* in_sizes, int n_in,
                              void* d_out, int out_size, void* d_ws, size_t ws_size,
                              hipStream_t stream) {
    (void)in_sizes; (void)n_in; (void)out_size; (void)ws_size;
    const float* x      = (const float*)d_in[0];
    const float* coords = (const float*)d_in[1];
    const float* wq     = (const float*)d_in[2];
    const float* wk     = (const float*)d_in[3];
    const float* wv     = (const float*)d_in[4];
    const float* w_rpe  = (const float*)d_in[5];
    const float* w_out  = (const float*)d_in[6];
    const float* b_out  = (const float*)d_in[7];
    const float* g1     = (const float*)d_in[8];
    const float* be1    = (const float*)d_in[9];
    const float* g2     = (const float*)d_in[10];
    const float* be2    = (const float*)d_in[11];
    const float* ffw1   = (const float*)d_in[12];
    const float* ffb1   = (const float*)d_in[13];
    const float* ffw2   = (const float*)d_in[14];
    const float* ffb2   = (const float*)d_in[15];
    float* out = (float*)d_out;

    char* ws = (char*)d_ws;
    unsigned int* hseg    = (unsigned int*)(ws);                     // 256 KB
    unsigned int* locmemb = (unsigned int*)(ws + 512 * 1024);        // 256 KB
    unsigned int* keyarr  = (unsigned int*)(ws + 768 * 1024);        // 256 KB
    unsigned int* order   = (unsigned int*)(ws + 1024 * 1024);       // 256 KB
    float*        w2      = (float*)(ws + 1280 * 1024);              // 16 f32
    unsigned short* wqkvb = (unsigned short*)(ws + 1536 * 1024);     // 48 KB
    unsigned short* woutb = wqkvb + 24576;
    unsigned short* ff1b  = woutb + 8192;
    unsigned short* ff2b  = ff1b + 1024;

    kprep  <<<256, 256, 0, stream>>>(coords, wq, wk, wv, w_out, ffw1, ffw2, w_rpe,
                                     hseg, locmemb, keyarr,
                                     wqkvb, woutb, ff1b, ff2b, w2);
    kbucket<<<256, 512, 0, stream>>>(hseg, locmemb, keyarr, order);
    kattn  <<<1024, 256, 0, stream>>>(x, g1, be1, wqkvb, order, coords, w2,
                                      woutb, b_out, g2, be2,
                                      ff1b, ffb1, ff2b, ffb2, out);
}